// Round 3
// baseline (122.467 us; speedup 1.0000x reference)
//
#include <hip/hip_runtime.h>

// Quanv: 3x3 VALID conv, x:(32,64,64,64) f32, w:(128,64,9) f32.
// Output layout replicates reference bug: out[((oc*B + b)*Ho + ho)*Wo + wo].
//
// R3: 32x32x16 bf16 MFMA, barrier-free tap loop.
//  - transpose_x: x -> xT[b][h][col][c] bf16, c as 8 chunks of 8, chunk q at
//    q ^ (col&7) (keeps ds_read_b128 conflict-free AND glds-verbatim).
//  - pack_w: w -> wT[tap][oc][c] bf16, chunk q at q ^ (oc&7).
//  - main: 512 blocks (16 ho-tiles x 32 b), 4 waves = 4 output rows.
//    Wave = 1 row x 128 oc x 64 wo = 4x2 tiles of mfma_f32_32x32x16_bf16.
//    A-frags (weights) come from GLOBAL (L2-resident, all blocks same addrs)
//    into registers each tap -> NO weight LDS, NO barriers after staging.
//    LDS = x tile only: 6 rows x 66 cols x 128 B = 49.5 KB -> 2-3 blocks/CU,
//    waves drift freely so stage/compute/store phases overlap.

typedef __attribute__((ext_vector_type(8))) short short8;
typedef __attribute__((ext_vector_type(16))) float f32x16;
typedef __attribute__((ext_vector_type(4))) unsigned int uint4v;

__device__ __forceinline__ unsigned short f2bf(float f) {
    unsigned u = __builtin_bit_cast(unsigned, f);
    u = (u + 0x7FFFu + ((u >> 16) & 1u)) >> 16;   // RNE
    return (unsigned short)u;
}

__device__ __forceinline__ void glds16(const void* g, void* s) {
    __builtin_amdgcn_global_load_lds(
        (const __attribute__((address_space(1))) unsigned int*)g,
        (__attribute__((address_space(3))) unsigned int*)s, 16, 0, 0);
}

// ---------- prep 1: x (b,c,h,w) f32 -> xT[b][h][col][c-swizzled] bf16 ----------
__global__ __launch_bounds__(256)
void transpose_x(const float* __restrict__ x, char* __restrict__ xT) {
    __shared__ float tile[64][65];          // [c][col], +1 pad
    const int tid = threadIdx.x;
    const int h = blockIdx.x, b = blockIdx.y;

    #pragma unroll
    for (int i = 0; i < 4; ++i) {
        const int idx = i * 256 + tid;
        const int c = idx >> 4, j = idx & 15;
        const float4 v = *(const float4*)(x + (size_t)(((b * 64 + c) * 64 + h) * 64 + j * 4));
        tile[c][j * 4 + 0] = v.x; tile[c][j * 4 + 1] = v.y;
        tile[c][j * 4 + 2] = v.z; tile[c][j * 4 + 3] = v.w;
    }
    __syncthreads();

    #pragma unroll
    for (int i = 0; i < 2; ++i) {
        const int idx = i * 256 + tid;
        const int col = idx >> 3, q = idx & 7;
        unsigned int wds[4];
        #pragma unroll
        for (int jj = 0; jj < 4; ++jj) {
            const unsigned short lo = f2bf(tile[q * 8 + 2 * jj + 0][col]);
            const unsigned short hi = f2bf(tile[q * 8 + 2 * jj + 1][col]);
            wds[jj] = (unsigned)lo | ((unsigned)hi << 16);
        }
        uint4v v; v[0] = wds[0]; v[1] = wds[1]; v[2] = wds[2]; v[3] = wds[3];
        *(uint4v*)(xT + (size_t)(((b * 64 + h) * 64 + col) * 128) + ((q ^ (col & 7)) * 16)) = v;
    }
}

// ---------- prep 2: w (oc, c, 9) f32 -> wT[tap][oc][c-swizzled] bf16 ----------
__global__ __launch_bounds__(256)
void pack_w(const float* __restrict__ w, char* __restrict__ wT) {
    const int id = blockIdx.x * 256 + threadIdx.x;   // 0..9215
    const int t = id >> 10;
    const int rem = id & 1023;
    const int oc = rem >> 3, q = rem & 7;
    unsigned int wds[4];
    #pragma unroll
    for (int jj = 0; jj < 4; ++jj) {
        const unsigned short lo = f2bf(w[(size_t)oc * 576 + (q * 8 + 2 * jj + 0) * 9 + t]);
        const unsigned short hi = f2bf(w[(size_t)oc * 576 + (q * 8 + 2 * jj + 1) * 9 + t]);
        wds[jj] = (unsigned)lo | ((unsigned)hi << 16);
    }
    uint4v v; v[0] = wds[0]; v[1] = wds[1]; v[2] = wds[2]; v[3] = wds[3];
    *(uint4v*)(wT + (size_t)(t * 16384 + oc * 128) + ((q ^ (oc & 7)) * 16)) = v;
}

// ---------- main MFMA kernel (32x32x16, barrier-free tap loop) ----------
#define ROWSTRIDE 8448   // 66 cols * 128 B (2 halo cols so kw-shifted reads stay in-bounds)

__global__ __launch_bounds__(256, 2)
void quanv_mfma32(const char* __restrict__ xT, const char* __restrict__ wT,
                  float* __restrict__ out) {
    __shared__ __align__(16) char sx[6 * ROWSTRIDE];   // 49.5 KB

    const int tid  = threadIdx.x;
    const int lane = tid & 63;
    const int wid  = tid >> 6;          // 0..3 = output row within tile
    const int hot  = blockIdx.x;        // 0..15
    const int b    = blockIdx.y;        // 0..31
    const int ho0  = hot * 4;

    // Stage 6 input rows (ho0..ho0+5, clamped) of xT: 48 chunks of 1 KB, async.
    for (int k = wid; k < 48; k += 4) {
        const int r = k >> 3, sub = k & 7;
        int gr = ho0 + r; if (gr > 63) gr = 63;
        glds16(xT + (size_t)((b * 64 + gr) * 8192 + sub * 1024 + lane * 16),
               sx + r * ROWSTRIDE + sub * 1024);
    }
    __syncthreads();   // vmcnt(0) drain + barrier: the ONLY barrier

    const int l31 = lane & 31;
    const int hi  = lane >> 5;          // 0..1
    const int ho  = ho0 + wid;

    // A-frag voffsets per k-chunk: oc = mt*32 + l31, q = kc*2 + hi
    int voff[4];
    #pragma unroll
    for (int kc = 0; kc < 4; ++kc)
        voff[kc] = l31 * 128 + (((kc * 2 + hi) ^ (l31 & 7)) * 16);

    f32x16 acc[4][2];
    #pragma unroll
    for (int mt = 0; mt < 4; ++mt)
        #pragma unroll
        for (int nt = 0; nt < 2; ++nt)
            #pragma unroll
            for (int e = 0; e < 16; ++e) acc[mt][nt][e] = 0.f;

    #pragma unroll
    for (int tap = 0; tap < 9; ++tap) {
        const int kh = tap / 3, kw = tap % 3;
        const char* wtap = wT + (size_t)tap * 16384;

        // Weights for this tap: 16 x 16B per lane, straight from L2.
        short8 a[4][4];                  // [kc][mt]
        #pragma unroll
        for (int kc = 0; kc < 4; ++kc)
            #pragma unroll
            for (int mt = 0; mt < 4; ++mt)
                a[kc][mt] = *(const short8*)(wtap + mt * 4096 + voff[kc]);

        const int colswz = (kw + l31) & 7;
        const int bbase  = (wid + kh) * ROWSTRIDE + (kw + l31) * 128;
        #pragma unroll
        for (int kc = 0; kc < 4; ++kc) {
            short8 bf[2];
            #pragma unroll
            for (int nt = 0; nt < 2; ++nt)
                bf[nt] = *(const short8*)(sx + bbase + nt * 4096 +
                                          (((kc * 2 + hi) ^ colswz) * 16));
            #pragma unroll
            for (int mt = 0; mt < 4; ++mt)
                #pragma unroll
                for (int nt = 0; nt < 2; ++nt)
                    acc[mt][nt] = __builtin_amdgcn_mfma_f32_32x32x16_bf16(
                        a[kc][mt], bf[nt], acc[mt][nt], 0, 0, 0);
        }
    }

    // Epilogue. C/D: col(wo)=lane&31, row(oc)= (reg&3)+8*(reg>>2)+4*(lane>>5).
    if (ho < 62) {
        #pragma unroll
        for (int mt = 0; mt < 4; ++mt) {
            #pragma unroll
            for (int r = 0; r < 16; ++r) {
                const int oc = mt * 32 + (r & 3) + 8 * (r >> 2) + 4 * hi;
                float* op = out + ((size_t)(oc * 32 + b) * 62 + ho) * 62;
                op[l31] = acc[mt][0][r];                      // wo 0..31
                if (l31 < 30) op[32 + l31] = acc[mt][1][r];   // wo 32..61
            }
        }
    }
}

// ---------- fallback: fp32 direct conv (used only if ws too small) ----------
#define CCH   8
#define OC_PT 8
#define ROWS  18
__global__ __launch_bounds__(256, 4)
void quanv_f32(const float* __restrict__ x, const float* __restrict__ w,
               float* __restrict__ out) {
    __shared__ float sx_raw[CCH * ROWS * 64 + 4];
    #define SX(cl, row, col) sx_raw[((cl) * ROWS + (row)) * 64 + (col)]
    const int tid = threadIdx.x;
    const int tx = tid & 15, ty = tid >> 4;
    const int hot = blockIdx.x, ocg = blockIdx.y, b = blockIdx.z;
    const int row0 = hot * 16, ho = row0 + ty, wo0 = tx * 4;
    const float* xb = x + (size_t)b * (64 * 64 * 64);
    const float* wb = w + (size_t)(ocg * OC_PT) * 576;
    float acc[OC_PT][4];
    #pragma unroll
    for (int o = 0; o < OC_PT; ++o)
        #pragma unroll
        for (int q = 0; q < 4; ++q) acc[o][q] = 0.f;
    for (int cc = 0; cc < 64; cc += CCH) {
        __syncthreads();
        #pragma unroll
        for (int j = 0; j < 9; ++j) {
            const int idx = j * 256 + tid;
            const int col4 = idx & 15, rowc = idx >> 4;
            const int row = rowc % ROWS, cl = rowc / ROWS;
            int gr = row0 + row; if (gr > 63) gr = 63;
            *(float4*)(&sx_raw[idx * 4]) =
                *(const float4*)(xb + ((size_t)(cc + cl) * 64 + gr) * 64 + col4 * 4);
        }
        __syncthreads();
        for (int cl = 0; cl < CCH; ++cl) {
            float xv[3][6];
            #pragma unroll
            for (int kh = 0; kh < 3; ++kh)
                #pragma unroll
                for (int j = 0; j < 6; ++j) xv[kh][j] = SX(cl, ty + kh, wo0 + j);
            const float* wc = wb + (size_t)(cc + cl) * 9;
            #pragma unroll
            for (int o = 0; o < OC_PT; ++o) {
                float wv[9];
                #pragma unroll
                for (int t = 0; t < 9; ++t) wv[t] = wc[(size_t)o * 576 + t];
                #pragma unroll
                for (int kh = 0; kh < 3; ++kh)
                    #pragma unroll
                    for (int kw = 0; kw < 3; ++kw) {
                        const float wvv = wv[kh * 3 + kw];
                        #pragma unroll
                        for (int q = 0; q < 4; ++q)
                            acc[o][q] = fmaf(xv[kh][kw + q], wvv, acc[o][q]);
                    }
            }
        }
    }
    if (ho < 62) {
        #pragma unroll
        for (int o = 0; o < OC_PT; ++o) {
            const int oc = ocg * OC_PT + o;
            float* op = out + ((size_t)(oc * 32 + b) * 62 + ho) * 62 + wo0;
            #pragma unroll
            for (int q = 0; q < 4; ++q)
                if (wo0 + q < 62) op[q] = acc[o][q];
        }
    }
    #undef SX
}

extern "C" void kernel_launch(void* const* d_in, const int* in_sizes, int n_in,
                              void* d_out, int out_size, void* d_ws, size_t ws_size,
                              hipStream_t stream) {
    const float* x = (const float*)d_in[0];
    const float* w = (const float*)d_in[1];
    float* out = (float*)d_out;

    const size_t XT_BYTES = 16777216;   // 32*64*64*64 bf16
    const size_t WT_BYTES = 147456;     // 9*128*64 bf16

    if (ws_size >= XT_BYTES + WT_BYTES) {
        char* xT = (char*)d_ws;
        char* wT = (char*)d_ws + XT_BYTES;
        transpose_x<<<dim3(64, 32), 256, 0, stream>>>(x, xT);
        pack_w<<<36, 256, 0, stream>>>(w, wT);
        quanv_mfma32<<<dim3(16, 32), 256, 0, stream>>>(xT, wT, out);
    } else {
        quanv_f32<<<dim3(4, 16, 32), 256, 0, stream>>>(x, w, out);
    }
}

// Round 4
// 117.717 us; speedup vs baseline: 1.0403x; 1.0403x over previous
//
#include <hip/hip_runtime.h>

// Quanv: 3x3 VALID conv, x:(32,64,64,64) f32, w:(128,64,9) f32.
// Output layout replicates reference bug: out[((oc*B + b)*Ho + ho)*Wo + wo].
//
// R4: 32x32x16 bf16 MFMA, barrier-free tap loop, weight-shared wave partition.
//  - transpose_x: x -> xT[b][h][col][c] bf16, c as 8 chunks of 8, chunk q at
//    q ^ (col&7) (conflict-free ds_read_b128 per lane-octet AND glds-verbatim).
//  - pack_w: w -> wT[tap][oc][c] bf16, chunk q at q ^ (oc&7).
//  - main: 512 blocks (16 ho-tiles x 32 b), 4 waves.
//    Wave = 2 rows x 64 oc (2 mt) x 64 wo (2 nt) -> 8 f32x16 acc (128 VGPR).
//    vs R3 (1 row x 4 mt): halves redundant weight L2 traffic (295->148 MB).
//    Tap loop: #pragma unroll 1 + depth-1 register prefetch of next tap's
//    A-frags -> live set ~210 VGPR, no spill, still ZERO barriers after stage.

typedef __attribute__((ext_vector_type(8))) short short8;
typedef __attribute__((ext_vector_type(16))) float f32x16;
typedef __attribute__((ext_vector_type(4))) unsigned int uint4v;

__device__ __forceinline__ unsigned short f2bf(float f) {
    unsigned u = __builtin_bit_cast(unsigned, f);
    u = (u + 0x7FFFu + ((u >> 16) & 1u)) >> 16;   // RNE
    return (unsigned short)u;
}

__device__ __forceinline__ void glds16(const void* g, void* s) {
    __builtin_amdgcn_global_load_lds(
        (const __attribute__((address_space(1))) unsigned int*)g,
        (__attribute__((address_space(3))) unsigned int*)s, 16, 0, 0);
}

// ---------- prep 1: x (b,c,h,w) f32 -> xT[b][h][col][c-swizzled] bf16 ----------
__global__ __launch_bounds__(256)
void transpose_x(const float* __restrict__ x, char* __restrict__ xT) {
    __shared__ float tile[64][65];          // [c][col], +1 pad
    const int tid = threadIdx.x;
    const int h = blockIdx.x, b = blockIdx.y;

    #pragma unroll
    for (int i = 0; i < 4; ++i) {
        const int idx = i * 256 + tid;
        const int c = idx >> 4, j = idx & 15;
        const float4 v = *(const float4*)(x + (size_t)(((b * 64 + c) * 64 + h) * 64 + j * 4));
        tile[c][j * 4 + 0] = v.x; tile[c][j * 4 + 1] = v.y;
        tile[c][j * 4 + 2] = v.z; tile[c][j * 4 + 3] = v.w;
    }
    __syncthreads();

    #pragma unroll
    for (int i = 0; i < 2; ++i) {
        const int idx = i * 256 + tid;
        const int col = idx >> 3, q = idx & 7;
        unsigned int wds[4];
        #pragma unroll
        for (int jj = 0; jj < 4; ++jj) {
            const unsigned short lo = f2bf(tile[q * 8 + 2 * jj + 0][col]);
            const unsigned short hi = f2bf(tile[q * 8 + 2 * jj + 1][col]);
            wds[jj] = (unsigned)lo | ((unsigned)hi << 16);
        }
        uint4v v; v[0] = wds[0]; v[1] = wds[1]; v[2] = wds[2]; v[3] = wds[3];
        *(uint4v*)(xT + (size_t)(((b * 64 + h) * 64 + col) * 128) + ((q ^ (col & 7)) * 16)) = v;
    }
}

// ---------- prep 2: w (oc, c, 9) f32 -> wT[tap][oc][c-swizzled] bf16 ----------
__global__ __launch_bounds__(256)
void pack_w(const float* __restrict__ w, char* __restrict__ wT) {
    const int id = blockIdx.x * 256 + threadIdx.x;   // 0..9215
    const int t = id >> 10;
    const int rem = id & 1023;
    const int oc = rem >> 3, q = rem & 7;
    unsigned int wds[4];
    #pragma unroll
    for (int jj = 0; jj < 4; ++jj) {
        const unsigned short lo = f2bf(w[(size_t)oc * 576 + (q * 8 + 2 * jj + 0) * 9 + t]);
        const unsigned short hi = f2bf(w[(size_t)oc * 576 + (q * 8 + 2 * jj + 1) * 9 + t]);
        wds[jj] = (unsigned)lo | ((unsigned)hi << 16);
    }
    uint4v v; v[0] = wds[0]; v[1] = wds[1]; v[2] = wds[2]; v[3] = wds[3];
    *(uint4v*)(wT + (size_t)(t * 16384 + oc * 128) + ((q ^ (oc & 7)) * 16)) = v;
}

// ---------- main MFMA kernel ----------
#define ROWSTRIDE 8448   // 66 cols * 128 B (2 halo cols; reads there feed masked lanes only)

__global__ __launch_bounds__(256, 2)
void quanv_mfma32(const char* __restrict__ xT, const char* __restrict__ wT,
                  float* __restrict__ out) {
    __shared__ __align__(16) char sx[6 * ROWSTRIDE];   // 49.5 KB

    const int tid  = threadIdx.x;
    const int lane = tid & 63;
    const int wid  = tid >> 6;
    const int hot  = blockIdx.x;        // 0..15
    const int b    = blockIdx.y;        // 0..31
    const int ho0  = hot * 4;

    // Stage 6 input rows (ho0..ho0+5, clamped) of xT: 48 chunks of 1 KB, async.
    for (int k = wid; k < 48; k += 4) {
        const int r = k >> 3, sub = k & 7;
        int gr = ho0 + r; if (gr > 63) gr = 63;
        glds16(xT + (size_t)((b * 64 + gr) * 8192 + sub * 1024 + lane * 16),
               sx + r * ROWSTRIDE + sub * 1024);
    }
    __syncthreads();   // vmcnt(0) drain + barrier: the ONLY barrier

    const int l31 = lane & 31;
    const int hi  = lane >> 5;          // 0..1
    const int rp  = wid >> 1;           // row pair: rows 2rp, 2rp+1
    const int oh  = wid & 1;            // oc half: mt = oh*2 + {0,1}

    // A-frag voffsets per k-chunk: oc_in_tile = l31, chunk q = kc*2 + hi
    int voff[4];
    #pragma unroll
    for (int kc = 0; kc < 4; ++kc)
        voff[kc] = l31 * 128 + (((kc * 2 + hi) ^ (l31 & 7)) * 16);

    f32x16 acc[2][2][2];   // [r][mtl][nt]
    #pragma unroll
    for (int r = 0; r < 2; ++r)
        #pragma unroll
        for (int mtl = 0; mtl < 2; ++mtl)
            #pragma unroll
            for (int nt = 0; nt < 2; ++nt)
                #pragma unroll
                for (int e = 0; e < 16; ++e) acc[r][mtl][nt][e] = 0.f;

    const char* wt0 = wT + (size_t)(oh * 2) * 4096;  // this wave's oc half
    short8 acur[4][2];                               // [kc][mtl]
    #pragma unroll
    for (int kc = 0; kc < 4; ++kc)
        #pragma unroll
        for (int mtl = 0; mtl < 2; ++mtl)
            acur[kc][mtl] = *(const short8*)(wt0 + mtl * 4096 + voff[kc]);

    int kh = 0, kw = 0;
    const char* wt = wt0;
    #pragma unroll 1
    for (int tap = 0; tap < 9; ++tap) {
        // depth-1 prefetch of next tap's weights (L2-resident; hides latency)
        short8 anxt[4][2];
        const char* wn = wt + 16384;
        if (tap < 8) {
            #pragma unroll
            for (int kc = 0; kc < 4; ++kc)
                #pragma unroll
                for (int mtl = 0; mtl < 2; ++mtl)
                    anxt[kc][mtl] = *(const short8*)(wn + mtl * 4096 + voff[kc]);
        }

        const int colswz = (kw + l31) & 7;
        const int cbase  = (kw + l31) * 128;
        #pragma unroll
        for (int kc = 0; kc < 4; ++kc) {
            const int chs = (((kc * 2 + hi) ^ colswz) * 16);
            #pragma unroll
            for (int r = 0; r < 2; ++r) {
                const char* bp = sx + (2 * rp + r + kh) * ROWSTRIDE + cbase + chs;
                short8 bf0 = *(const short8*)(bp);
                short8 bf1 = *(const short8*)(bp + 4096);
                #pragma unroll
                for (int mtl = 0; mtl < 2; ++mtl) {
                    acc[r][mtl][0] = __builtin_amdgcn_mfma_f32_32x32x16_bf16(
                        acur[kc][mtl], bf0, acc[r][mtl][0], 0, 0, 0);
                    acc[r][mtl][1] = __builtin_amdgcn_mfma_f32_32x32x16_bf16(
                        acur[kc][mtl], bf1, acc[r][mtl][1], 0, 0, 0);
                }
            }
        }

        #pragma unroll
        for (int kc = 0; kc < 4; ++kc)
            #pragma unroll
            for (int mtl = 0; mtl < 2; ++mtl)
                acur[kc][mtl] = anxt[kc][mtl];
        wt = wn;
        if (++kw == 3) { kw = 0; ++kh; }
    }

    // Epilogue. C/D: col(wo)=lane&31, row(oc)=(reg&3)+8*(reg>>2)+4*(lane>>5).
    #pragma unroll
    for (int r = 0; r < 2; ++r) {
        const int ho = ho0 + 2 * rp + r;
        if (ho < 62) {
            #pragma unroll
            for (int mtl = 0; mtl < 2; ++mtl) {
                #pragma unroll
                for (int g = 0; g < 16; ++g) {
                    const int oc = (oh * 2 + mtl) * 32 + (g & 3) + 8 * (g >> 2) + 4 * hi;
                    float* op = out + ((size_t)(oc * 32 + b) * 62 + ho) * 62;
                    op[l31] = acc[r][mtl][0][g];                      // wo 0..31
                    if (l31 < 30) op[32 + l31] = acc[r][mtl][1][g];   // wo 32..61
                }
            }
        }
    }
}

// ---------- fallback: fp32 direct conv (used only if ws too small) ----------
#define CCH   8
#define OC_PT 8
#define ROWS  18
__global__ __launch_bounds__(256, 4)
void quanv_f32(const float* __restrict__ x, const float* __restrict__ w,
               float* __restrict__ out) {
    __shared__ float sx_raw[CCH * ROWS * 64 + 4];
    #define SX(cl, row, col) sx_raw[((cl) * ROWS + (row)) * 64 + (col)]
    const int tid = threadIdx.x;
    const int tx = tid & 15, ty = tid >> 4;
    const int hot = blockIdx.x, ocg = blockIdx.y, b = blockIdx.z;
    const int row0 = hot * 16, ho = row0 + ty, wo0 = tx * 4;
    const float* xb = x + (size_t)b * (64 * 64 * 64);
    const float* wb = w + (size_t)(ocg * OC_PT) * 576;
    float acc[OC_PT][4];
    #pragma unroll
    for (int o = 0; o < OC_PT; ++o)
        #pragma unroll
        for (int q = 0; q < 4; ++q) acc[o][q] = 0.f;
    for (int cc = 0; cc < 64; cc += CCH) {
        __syncthreads();
        #pragma unroll
        for (int j = 0; j < 9; ++j) {
            const int idx = j * 256 + tid;
            const int col4 = idx & 15, rowc = idx >> 4;
            const int row = rowc % ROWS, cl = rowc / ROWS;
            int gr = row0 + row; if (gr > 63) gr = 63;
            *(float4*)(&sx_raw[idx * 4]) =
                *(const float4*)(xb + ((size_t)(cc + cl) * 64 + gr) * 64 + col4 * 4);
        }
        __syncthreads();
        for (int cl = 0; cl < CCH; ++cl) {
            float xv[3][6];
            #pragma unroll
            for (int kh = 0; kh < 3; ++kh)
                #pragma unroll
                for (int j = 0; j < 6; ++j) xv[kh][j] = SX(cl, ty + kh, wo0 + j);
            const float* wc = wb + (size_t)(cc + cl) * 9;
            #pragma unroll
            for (int o = 0; o < OC_PT; ++o) {
                float wv[9];
                #pragma unroll
                for (int t = 0; t < 9; ++t) wv[t] = wc[(size_t)o * 576 + t];
                #pragma unroll
                for (int kh = 0; kh < 3; ++kh)
                    #pragma unroll
                    for (int kw = 0; kw < 3; ++kw) {
                        const float wvv = wv[kh * 3 + kw];
                        #pragma unroll
                        for (int q = 0; q < 4; ++q)
                            acc[o][q] = fmaf(xv[kh][kw + q], wvv, acc[o][q]);
                    }
            }
        }
    }
    if (ho < 62) {
        #pragma unroll
        for (int o = 0; o < OC_PT; ++o) {
            const int oc = ocg * OC_PT + o;
            float* op = out + ((size_t)(oc * 32 + b) * 62 + ho) * 62 + wo0;
            #pragma unroll
            for (int q = 0; q < 4; ++q)
                if (wo0 + q < 62) op[q] = acc[o][q];
        }
    }
    #undef SX
}

extern "C" void kernel_launch(void* const* d_in, const int* in_sizes, int n_in,
                              void* d_out, int out_size, void* d_ws, size_t ws_size,
                              hipStream_t stream) {
    const float* x = (const float*)d_in[0];
    const float* w = (const float*)d_in[1];
    float* out = (float*)d_out;

    const size_t XT_BYTES = 16777216;   // 32*64*64*64 bf16
    const size_t WT_BYTES = 147456;     // 9*128*64 bf16

    if (ws_size >= XT_BYTES + WT_BYTES) {
        char* xT = (char*)d_ws;
        char* wT = (char*)d_ws + XT_BYTES;
        transpose_x<<<dim3(64, 32), 256, 0, stream>>>(x, xT);
        pack_w<<<36, 256, 0, stream>>>(w, wT);
        quanv_mfma32<<<dim3(16, 32), 256, 0, stream>>>(xT, wT, out);
    } else {
        quanv_f32<<<dim3(4, 16, 32), 256, 0, stream>>>(x, w, out);
    }
}